// Round 5
// baseline (832.595 us; speedup 1.0000x reference)
//
#include <hip/hip_runtime.h>
#include <math.h>

#define Bn 4
#define Nn 1024
#define En 65536
#define Fn 96
#define FEn 32
#define Hn 12
// K dim for message MLP: 2F+FE = 224

// ---- MEASUREMENT ROUND: rep-loops expose per-kernel time in rocprof ----
// scan x21 (non-final reps use dummy counter gcnt[1] -> same contention, no
// correctness impact), msg x6 (agg atomics last rep only), attn x5 (idempotent).
#define REP_SCAN 21
#define REP_MSG  6
#define REP_ATTN 5

// ---- out layout (floats) ----
#define OUT_UPD  0
#define OUT_WM   393216LL             // B*N*F
#define OUT_DIST 25559040LL           // + B*E*F
#define OUT_EDGE 25821184LL           // + B*E

// ---- ws layout (float words) ----
#define WS_AGG  0
#define WS_Q    393216
#define WS_K    786432
#define WS_V    1179648
#define WS_G    1572864
#define WS_AO   1966080
#define WS_LIST 2359296   // int: compacted active-edge ids (cap 65536)
#define WS_LW   2424832   // float: per-active gaussian weight
#define WS_CNT  2490368   // int[2]: active count (real, dummy)

#define MSG_WAVES 3328    // 832 blocks * 4 waves; >= expected actives (~3253)

__device__ __forceinline__ float gelu_exact(float x) {
    return 0.5f * x * (1.0f + erff(x * 0.70710678118654752f));
}

// Zero the inactive rows of one 256-edge chunk of out_wm (96 KB).
__device__ __forceinline__ void zero_wm_chunk(int c, const float* __restrict__ dist,
                                              const float* __restrict__ sigma,
                                              const float* __restrict__ beta,
                                              float* __restrict__ out_wm,
                                              int tid, int nthr, int* s_act) {
    if (tid < 256) {
        int ge = c * 256 + tid;
        float d = dist[ge];
        float sg = sigma[0], bt = beta[0];
        float t = d * d / (2.0f * sg * sg);
        s_act[tid] = (powf(t, bt) < 90.0f) ? 1 : 0;
    }
    __syncthreads();
    const float4 z = make_float4(0.f, 0.f, 0.f, 0.f);
    float4* wm4 = (float4*)out_wm + (size_t)c * 6144;   // 256 rows * 24 float4
    for (int p = tid; p < 6144; p += nthr) {
        if (!s_act[p / 24]) wm4[p] = z;
    }
}

// Pass 0: zero agg (1.5 MB) + both counters.
__global__ void zero_kernel(float* __restrict__ agg, int* __restrict__ gcnt) {
    int i = blockIdx.x * 256 + threadIdx.x;
    const float4 z = make_float4(0.f, 0.f, 0.f, 0.f);
    float4* p = (float4*)agg;
    p[i] = z;
    p[i + 49152] = z;
    if (i == 0) { gcnt[0] = 0; gcnt[1] = 0; }
}

// Pass 1a (scan), x REP_SCAN. Non-final reps: identical work + atomics into
// gcnt[1] (dummy) -> measures contention; stores land at permuted positions
// in-cap (harmless, overwritten). Final rep: real gcnt[0], base 0.
__global__ void scan_kernel(const float* __restrict__ dist, const int* __restrict__ edges,
                            const float* __restrict__ sigma, const float* __restrict__ beta,
                            float* __restrict__ out_dist, float* __restrict__ out_edges,
                            int* __restrict__ glist, float* __restrict__ gw,
                            int* __restrict__ gcnt) {
    int tid = threadIdx.x;
    int ge = blockIdx.x * 256 + tid;
    for (int rep = 0; rep < REP_SCAN; ++rep) {
        float d = dist[ge];
        out_dist[ge] = d;
        int e0 = edges[2 * ge], e1 = edges[2 * ge + 1];
        *(float2*)&out_edges[2 * ge] = make_float2((float)e0, (float)e1);
        float sg = sigma[0], bt = beta[0];
        float t  = d * d / (2.0f * sg * sg);
        float tp = powf(t, bt);
        bool active = (tp < 90.0f);        // else w underflows f32 (ref < 1e-39)
        float w = active ? expf(-tp) : 0.0f;

        unsigned long long mask = __ballot(active);
        int lane = tid & 63;
        int lp = __popcll(mask & ((1ull << lane) - 1ull));
        int* cnt = (rep == REP_SCAN - 1) ? gcnt : gcnt + 1;
        int base = 0;
        if (lane == 0 && mask) base = atomicAdd(cnt, __popcll(mask));
        base = __shfl(base, 0);
        if (active) {
            int pos = base + lp;
            if (pos < 65536) { glist[pos] = ge; gw[pos] = w; }
        }
    }
}

// Pass 1b (msg), x REP_MSG. One wave per active edge. agg atomics gated to
// final rep; wm row stores idempotent across reps.
__global__ void msg_kernel(const int* __restrict__ glist, const float* __restrict__ gw,
                           const int* __restrict__ gcnt, const int* __restrict__ edges,
                           const float* __restrict__ nodes, const float* __restrict__ ef,
                           const float* __restrict__ Wm, const float* __restrict__ bm,
                           const float* __restrict__ g1, const float* __restrict__ b1,
                           float* __restrict__ out_wm, float* __restrict__ agg) {
    __shared__ float sin_s[4][232];
    int tid = threadIdx.x;
    int lane = tid & 63, wv = tid >> 6;
    int count = gcnt[0];
    if (count > 65536) count = 65536;
    int c2 = 64 + (lane & 31);             // upper lanes duplicate lanes 0..31
    for (int rep = 0; rep < REP_MSG; ++rep) {
        for (int ai = blockIdx.x * 4 + wv; ai < count; ai += MSG_WAVES) {
            int gei = glist[ai];
            float wgt = gw[ai];
            int b = gei >> 16;
            int e0 = edges[2 * gei], e1 = edges[2 * gei + 1];
            const float* n0 = nodes + ((size_t)b * Nn + e0) * 96;
            const float* n1 = nodes + ((size_t)b * Nn + e1) * 96;
            const float* ep = ef + (size_t)gei * 32;
            #pragma unroll
            for (int ii = 0; ii < 4; ++ii) {
                int i = ii * 64 + lane;
                if (i < 224) {
                    float v = (i < 96) ? n0[i] : (i < 192) ? n1[i - 96] : ep[i - 192];
                    sin_s[wv][i] = v;
                }
            }
            // wave-local LDS: write->read same wave, ordered, no barrier
            float acc1 = bm[lane];
            float acc2 = bm[c2];
            #pragma unroll 8
            for (int i = 0; i < 224; ++i) {
                float a = sin_s[wv][i];                    // LDS broadcast
                acc1 = fmaf(a, Wm[i * 96 + lane], acc1);
                acc2 = fmaf(a, Wm[i * 96 + c2], acc2);
            }
            float y1 = gelu_exact(acc1);
            float y2 = gelu_exact(acc2);
            float c2v = (lane < 32) ? y2 : 0.0f;
            float sum  = y1 + c2v;
            float sum2 = y1 * y1 + c2v * c2v;
            #pragma unroll
            for (int off = 1; off < 64; off <<= 1) {
                sum  += __shfl_xor(sum, off);
                sum2 += __shfl_xor(sum2, off);
            }
            float mean = sum * (1.0f / 96.0f);
            float var  = sum2 * (1.0f / 96.0f) - mean * mean;
            float rs   = rsqrtf(var + 1e-3f);
            float* aggp = agg + ((size_t)b * Nn + e1) * 96;
            float* wmp  = out_wm + (size_t)gei * 96;
            float o1 = ((y1 - mean) * rs * g1[lane] + b1[lane]) * wgt;
            wmp[lane] = o1;
            if (rep == REP_MSG - 1) atomicAdd(&aggp[lane], o1);
            if (lane < 32) {
                float o2 = ((y2 - mean) * rs * g1[c2] + b1[c2]) * wgt;
                wmp[c2] = o2;
                if (rep == REP_MSG - 1) atomicAdd(&aggp[c2], o2);
            }
        }
    }
}

// Pass 2: q/k/v/gate projections (unchanged from round 4).
__global__ void proj_kernel(const float* __restrict__ nodes, const float* __restrict__ agg,
                            const float* __restrict__ Wq, const float* __restrict__ bq,
                            const float* __restrict__ Wk, const float* __restrict__ bk,
                            const float* __restrict__ Wv, const float* __restrict__ bv,
                            const float* __restrict__ Wg, const float* __restrict__ bg,
                            float* __restrict__ qo, float* __restrict__ ko,
                            float* __restrict__ vo, float* __restrict__ go,
                            const float* __restrict__ dist, const float* __restrict__ sigma,
                            const float* __restrict__ beta, float* __restrict__ out_wm) {
    __shared__ float xs[32][200];   // padded; row byte-stride 800 = 50*16 (16B aligned)
    __shared__ float Wt[64 * 96];
    __shared__ int s_act[256];
    int tid = threadIdx.x;
    int m = blockIdx.y;
    if (m == 0) {
        zero_wm_chunk(768 + blockIdx.x, dist, sigma, beta, out_wm, tid, 256, s_act);
    }
    const float* W    = (m == 0) ? Wq : (m == 1) ? Wk : (m == 2) ? Wv : Wg;
    const float* bias = (m == 0) ? bq : (m == 1) ? bk : (m == 2) ? bv : bg;
    float* outp       = (m == 0) ? qo : (m == 1) ? ko : (m == 2) ? vo : go;
    int row0 = blockIdx.x * 32;
    int b = row0 >> 10, n0 = row0 & 1023;
    for (int i = tid; i < 32 * 192; i += 256) {
        int r = i / 192, k = i % 192;
        size_t row = row0 + r;
        xs[r][k] = (k < 96) ? nodes[row * 96 + k] : agg[row * 96 + (k - 96)];
    }
    int rg = tid >> 4;              // 0..15 (2 rows each)
    int cg = tid & 15;              // 0..15 (6 cols each)
    float acc[12];
    #pragma unroll
    for (int c = 0; c < 12; ++c) acc[c] = 0.0f;
    for (int kc = 0; kc < 3; ++kc) {
        __syncthreads();
        {
            float4* Wt4 = (float4*)Wt;
            const float4* Wg4 = (const float4*)(W + kc * 64 * 96);
            for (int i = tid; i < 1536; i += 256) Wt4[i] = Wg4[i];
        }
        __syncthreads();
        #pragma unroll 4
        for (int k = 0; k < 64; ++k) {
            float a0 = xs[rg * 2 + 0][kc * 64 + k];
            float a1 = xs[rg * 2 + 1][kc * 64 + k];
            #pragma unroll
            for (int c = 0; c < 6; ++c) {
                float wv_ = Wt[k * 96 + cg * 6 + c];
                acc[c]     = fmaf(a0, wv_, acc[c]);
                acc[6 + c] = fmaf(a1, wv_, acc[6 + c]);
            }
        }
    }
    // epilogue into LDS (cols 0..95 don't overlap kc=2's read range 128..191)
    #pragma unroll
    for (int i = 0; i < 2; ++i) {
        #pragma unroll
        for (int c = 0; c < 6; ++c) {
            int col = cg * 6 + c;
            float v = acc[i * 6 + c] + bias[col];
            if (m == 3) v = 1.0f / (1.0f + expf(-v));
            xs[rg * 2 + i][col] = v;
        }
    }
    __syncthreads();
    // coalesced store: per head h, 32 rows * 8 floats = contiguous 64 float4
    float4* out4 = (float4*)outp;
    for (int j = tid; j < 768; j += 256) {
        int h = j >> 6, idx = j & 63;
        int r = idx >> 1, half = idx & 1;
        float4 v = *(const float4*)&xs[r][h * 8 + half * 4];
        out4[(((size_t)b * Hn + h) * Nn + n0) * 2 + idx] = v;
    }
}

// Pass 3: split-KV attention, no-max softmax (round 4), x REP_ATTN.
__global__ __launch_bounds__(512, 6) void attn_kernel(
        const float* __restrict__ qp, const float* __restrict__ kp,
        const float* __restrict__ vp, const float* __restrict__ gp,
        float* __restrict__ ao,
        const float* __restrict__ dist, const float* __restrict__ sigma,
        const float* __restrict__ beta, float* __restrict__ out_wm) {
    __shared__ float sl[512];
    __shared__ float sacc[512][9];
    __shared__ int s_act[256];
    int tid = threadIdx.x;
    zero_wm_chunk(blockIdx.y * 16 + blockIdx.x, dist, sigma, beta, out_wm, tid, 512, s_act);
    int bh = blockIdx.y;                    // b*H + h
    int lane = tid & 63;
    int w = __builtin_amdgcn_readfirstlane(tid >> 6);
    int n = blockIdx.x * 64 + lane;
    size_t hb = (size_t)bh * (Nn * 8);
    size_t qoff = hb + (size_t)n * 8;

    const float scale = 0.35355339059327376f;  // 1/sqrt(8)
    float4 q0 = *(const float4*)&qp[qoff];
    float4 q1 = *(const float4*)&qp[qoff + 4];
    q0.x *= scale; q0.y *= scale; q0.z *= scale; q0.w *= scale;
    q1.x *= scale; q1.y *= scale; q1.z *= scale; q1.w *= scale;

    const float4* kc4 = (const float4*)(kp + hb) + (size_t)w * 256;  // 128 keys
    const float4* vc4 = (const float4*)(vp + hb) + (size_t)w * 256;

    for (int rep = 0; rep < REP_ATTN; ++rep) {
        __syncthreads();   // protect sl/sacc against previous rep's epilogue readers

        float l = 0.0f;
        float a0 = 0, a1 = 0, a2 = 0, a3 = 0, a4 = 0, a5 = 0, a6 = 0, a7 = 0;
        for (int g = 0; g < 32; ++g) {      // 4 keys per group
            float4 T[8];
            #pragma unroll
            for (int i = 0; i < 8; ++i) T[i] = kc4[g * 8 + i];   // K group
            float s[4];
            #pragma unroll
            for (int jj = 0; jj < 4; ++jj) {
                float4 k0 = T[jj * 2], k1 = T[jj * 2 + 1];
                s[jj] = q0.x * k0.x + q0.y * k0.y + q0.z * k0.z + q0.w * k0.w +
                        q1.x * k1.x + q1.y * k1.y + q1.z * k1.z + q1.w * k1.w;
            }
            #pragma unroll
            for (int i = 0; i < 8; ++i) T[i] = vc4[g * 8 + i];   // reuse regs: V group
            float p[4];
            #pragma unroll
            for (int jj = 0; jj < 4; ++jj) p[jj] = __expf(s[jj]);
            l += (p[0] + p[1]) + (p[2] + p[3]);
            #pragma unroll
            for (int jj = 0; jj < 4; ++jj) {
                float4 v0 = T[jj * 2], v1 = T[jj * 2 + 1];
                a0 = fmaf(p[jj], v0.x, a0);  a1 = fmaf(p[jj], v0.y, a1);
                a2 = fmaf(p[jj], v0.z, a2);  a3 = fmaf(p[jj], v0.w, a3);
                a4 = fmaf(p[jj], v1.x, a4);  a5 = fmaf(p[jj], v1.y, a5);
                a6 = fmaf(p[jj], v1.z, a6);  a7 = fmaf(p[jj], v1.w, a7);
            }
        }
        sl[tid] = l;
        sacc[tid][0] = a0; sacc[tid][1] = a1; sacc[tid][2] = a2; sacc[tid][3] = a3;
        sacc[tid][4] = a4; sacc[tid][5] = a5; sacc[tid][6] = a6; sacc[tid][7] = a7;
        __syncthreads();
        if (tid < 64) {
            float L = 0.0f;
            float o[8] = {0, 0, 0, 0, 0, 0, 0, 0};
            #pragma unroll
            for (int i = 0; i < 8; ++i) {
                L += sl[tid + 64 * i];
                #pragma unroll
                for (int d = 0; d < 8; ++d)
                    o[d] += sacc[tid + 64 * i][d];
            }
            float invL = 1.0f / L;
            float4 g0 = *(const float4*)&gp[qoff];
            float4 g1v = *(const float4*)&gp[qoff + 4];
            float4 r0 = make_float4(o[0] * invL * g0.x, o[1] * invL * g0.y,
                                    o[2] * invL * g0.z, o[3] * invL * g0.w);
            float4 r1 = make_float4(o[4] * invL * g1v.x, o[5] * invL * g1v.y,
                                    o[6] * invL * g1v.z, o[7] * invL * g1v.w);
            *(float4*)&ao[qoff] = r0;
            *(float4*)&ao[qoff + 4] = r1;
        }
    }
}

// Pass 4: out @ Wo + bo -> GELU -> LayerNorm (unchanged from round 4).
__global__ __launch_bounds__(512) void out_kernel(
        const float* __restrict__ ao, const float* __restrict__ Wo,
        const float* __restrict__ bo, const float* __restrict__ g2,
        const float* __restrict__ b2, float* __restrict__ out0,
        const float* __restrict__ dist, const float* __restrict__ sigma,
        const float* __restrict__ beta, float* __restrict__ out_wm) {
    __shared__ float Wsh[96 * 96];
    __shared__ float as_[32][104];   // row byte-stride 416 = 26*16 (16B aligned)
    __shared__ int s_act[256];
    int tid = threadIdx.x;
    zero_wm_chunk(896 + blockIdx.x, dist, sigma, beta, out_wm, tid, 512, s_act);
    int row0 = blockIdx.x * 32;
    int b = row0 >> 10, n0 = row0 & 1023;
    {
        float4* W4 = (float4*)Wsh;
        const float4* Wg4 = (const float4*)Wo;
        for (int i = tid; i < 2304; i += 512) W4[i] = Wg4[i];
    }
    const float4* ao4 = (const float4*)ao;
    for (int j = tid; j < 768; j += 512) {
        int h = j >> 6, idx = j & 63;
        int r = idx >> 1, half = idx & 1;
        float4 v = ao4[(((size_t)b * Hn + h) * Nn + n0) * 2 + idx];
        *(float4*)&as_[r][h * 8 + half * 4] = v;
    }
    __syncthreads();
    int r = tid >> 4, cg = tid & 15;   // 32 rows, 6 cols per thread
    float acc[6];
    #pragma unroll
    for (int c = 0; c < 6; ++c) acc[c] = 0.0f;
    for (int k = 0; k < 96; ++k) {
        float a = as_[r][k];
        #pragma unroll
        for (int c = 0; c < 6; ++c)
            acc[c] = fmaf(a, Wsh[k * 96 + cg * 6 + c], acc[c]);
    }
    float yv[6];
    float sum = 0.0f, sum2 = 0.0f;
    #pragma unroll
    for (int c = 0; c < 6; ++c) {
        float t = acc[c] + bo[cg * 6 + c];
        float g = gelu_exact(t);
        yv[c] = g;
        sum += g; sum2 += g * g;
    }
    #pragma unroll
    for (int off = 1; off < 16; off <<= 1) {
        sum  += __shfl_xor(sum, off);
        sum2 += __shfl_xor(sum2, off);
    }
    float mean = sum * (1.0f / 96.0f);
    float var  = sum2 * (1.0f / 96.0f) - mean * mean;
    float rs   = rsqrtf(var + 1e-3f);
    size_t row = row0 + r;
    #pragma unroll
    for (int c = 0; c < 6; ++c)
        out0[row * 96 + cg * 6 + c] = (yv[c] - mean) * rs * g2[cg * 6 + c] + b2[cg * 6 + c];
}

extern "C" void kernel_launch(void* const* d_in, const int* in_sizes, int n_in,
                              void* d_out, int out_size, void* d_ws, size_t ws_size,
                              hipStream_t stream) {
    const float* nodes = (const float*)d_in[0];
    const float* ef    = (const float*)d_in[1];
    const float* dist  = (const float*)d_in[2];
    const int*   edges = (const int*)d_in[3];
    const float* Wm = (const float*)d_in[4];
    const float* bm = (const float*)d_in[5];
    const float* g1 = (const float*)d_in[6];
    const float* b1 = (const float*)d_in[7];
    const float* Wq = (const float*)d_in[8];
    const float* bq = (const float*)d_in[9];
    const float* Wk = (const float*)d_in[10];
    const float* bk = (const float*)d_in[11];
    const float* Wv = (const float*)d_in[12];
    const float* bv = (const float*)d_in[13];
    const float* Wg = (const float*)d_in[14];
    const float* bg = (const float*)d_in[15];
    const float* Wo = (const float*)d_in[16];
    const float* bo = (const float*)d_in[17];
    const float* g2 = (const float*)d_in[18];
    const float* b2 = (const float*)d_in[19];
    const float* sigma = (const float*)d_in[20];
    const float* beta  = (const float*)d_in[21];

    float* out = (float*)d_out;
    float* ws  = (float*)d_ws;

    float* agg  = ws + WS_AGG;
    float* qb   = ws + WS_Q;
    float* kb   = ws + WS_K;
    float* vb   = ws + WS_V;
    float* gwb  = ws + WS_G;
    float* aob  = ws + WS_AO;
    int*   glist = (int*)(ws + WS_LIST);
    float* glw   = ws + WS_LW;
    int*   gcnt  = (int*)(ws + WS_CNT);

    zero_kernel<<<192, 256, 0, stream>>>(agg, gcnt);

    scan_kernel<<<Bn * En / 256, 256, 0, stream>>>(
        dist, edges, sigma, beta, out + OUT_DIST, out + OUT_EDGE, glist, glw, gcnt);

    msg_kernel<<<MSG_WAVES / 4, 256, 0, stream>>>(
        glist, glw, gcnt, edges, nodes, ef, Wm, bm, g1, b1, out + OUT_WM, agg);

    dim3 gp_(128, 4);
    proj_kernel<<<gp_, 256, 0, stream>>>(
        nodes, agg, Wq, bq, Wk, bk, Wv, bv, Wg, bg, qb, kb, vb, gwb,
        dist, sigma, beta, out + OUT_WM);

    dim3 ga(16, Bn * Hn);
    attn_kernel<<<ga, 512, 0, stream>>>(qb, kb, vb, gwb, aob,
                                        dist, sigma, beta, out + OUT_WM);

    out_kernel<<<Bn * Nn / 32, 512, 0, stream>>>(aob, Wo, bo, g2, b2, out + OUT_UPD,
                                                 dist, sigma, beta, out + OUT_WM);
}

// Round 6
// 113.874 us; speedup vs baseline: 7.3115x; 7.3115x over previous
//
#include <hip/hip_runtime.h>
#include <math.h>

#define Bn 4
#define Nn 1024
#define En 65536
#define Fn 96
#define FEn 32
#define Hn 12
// K dim for message MLP: 2F+FE = 224

// ---- out layout (floats) ----
#define OUT_UPD  0
#define OUT_WM   393216LL             // B*N*F
#define OUT_DIST 25559040LL           // + B*E*F
#define OUT_EDGE 25821184LL           // + B*E

// ---- ws layout (float words) ----
#define WS_AGG  0
#define WS_Q    393216
#define WS_K    786432
#define WS_V    1179648
#define WS_G    1572864
#define WS_AO   1966080
#define WS_LIST 2359296   // int: compacted active-edge ids (cap 65536)
#define WS_LW   2424832   // float: per-active gaussian weight
#define WS_CNT  2490368   // int: active count

#define MSG_NWAVES 1024   // 256 blocks * 4 waves; 4 edges/wave -> 4096 cap/round

__device__ __forceinline__ float gelu_exact(float x) {
    return 0.5f * x * (1.0f + erff(x * 0.70710678118654752f));
}

// Zero the inactive rows of one 256-edge chunk of out_wm (96 KB).
// Active test is bitwise-identical to scan's, so active/inactive rows partition.
__device__ __forceinline__ void zero_wm_chunk(int c, const float* __restrict__ dist,
                                              const float* __restrict__ sigma,
                                              const float* __restrict__ beta,
                                              float* __restrict__ out_wm,
                                              int tid, int nthr, int* s_act) {
    if (tid < 256) {
        int ge = c * 256 + tid;
        float d = dist[ge];
        float sg = sigma[0], bt = beta[0];
        float t = d * d / (2.0f * sg * sg);
        s_act[tid] = (powf(t, bt) < 90.0f) ? 1 : 0;
    }
    __syncthreads();
    const float4 z = make_float4(0.f, 0.f, 0.f, 0.f);
    float4* wm4 = (float4*)out_wm + (size_t)c * 6144;   // 256 rows * 24 float4
    for (int p = tid; p < 6144; p += nthr) {
        if (!s_act[p / 24]) wm4[p] = z;
    }
}

// Pass 0: zero agg (1.5 MB) + counter.
__global__ void zero_kernel(float* __restrict__ agg, int* __restrict__ gcnt) {
    int i = blockIdx.x * 256 + threadIdx.x;
    const float4 z = make_float4(0.f, 0.f, 0.f, 0.f);
    float4* p = (float4*)agg;
    p[i] = z;
    p[i + 49152] = z;
    if (i == 0) gcnt[0] = 0;
}

// Pass 1a (scan): per-edge gaussian gate; copy dist/edges to out; compact
// actives into a global list. ONE atomic per 1024-thread block (LDS
// aggregation): 256 serialized same-address atomics (~1.6us) instead of
// 4096 wave-atomics (~25us, round-5 measured 14.7cy/atomic serialization).
__global__ __launch_bounds__(1024) void scan_kernel(
        const float* __restrict__ dist, const int* __restrict__ edges,
        const float* __restrict__ sigma, const float* __restrict__ beta,
        float* __restrict__ out_dist, float* __restrict__ out_edges,
        int* __restrict__ glist, float* __restrict__ gw,
        int* __restrict__ gcnt) {
    __shared__ int wcnt[16], wbase[16], blkbase;
    int tid = threadIdx.x;
    int lane = tid & 63, wv = tid >> 6;
    int ge = blockIdx.x * 1024 + tid;
    float d = dist[ge];
    out_dist[ge] = d;
    int e0 = edges[2 * ge], e1 = edges[2 * ge + 1];
    *(float2*)&out_edges[2 * ge] = make_float2((float)e0, (float)e1);
    float sg = sigma[0], bt = beta[0];
    float t  = d * d / (2.0f * sg * sg);
    float tp = powf(t, bt);
    bool active = (tp < 90.0f);            // else w underflows f32 (ref < 1e-39)
    float w = active ? expf(-tp) : 0.0f;

    unsigned long long mask = __ballot(active);
    int lp = __popcll(mask & ((1ull << lane) - 1ull));
    if (lane == 0) wcnt[wv] = __popcll(mask);
    __syncthreads();
    if (tid == 0) {
        int a = 0;
        #pragma unroll
        for (int i = 0; i < 16; ++i) { wbase[i] = a; a += wcnt[i]; }
        blkbase = a ? atomicAdd(gcnt, a) : 0;
    }
    __syncthreads();
    if (active) {
        int pos = blkbase + wbase[wv] + lp;
        if (pos < 65536) { glist[pos] = ge; gw[pos] = w; }
    }
}

// Pass 1b (msg): FOUR edges per wave. Round-5 measured t_msg ~20us bound by
// streaming the whole 86KB Wm from L2 per edge (374 MB total). Processing an
// edge-quad per wave amortizes each Wm row load across 8 FMAs -> 94 MB L2
// traffic and 4x VALU density. a-vectors staged in LDS, broadcast-read.
__global__ __launch_bounds__(256) void msg_kernel(
        const int* __restrict__ glist, const float* __restrict__ gw,
        const int* __restrict__ gcnt, const int* __restrict__ edges,
        const float* __restrict__ nodes, const float* __restrict__ ef,
        const float* __restrict__ Wm, const float* __restrict__ bm,
        const float* __restrict__ g1, const float* __restrict__ b1,
        float* __restrict__ out_wm, float* __restrict__ agg) {
    __shared__ float sin_s[4][4][232];     // [wave][edge-in-quad][224+pad]
    int tid = threadIdx.x;
    int lane = tid & 63, wv = tid >> 6;
    int count = gcnt[0];
    if (count > 65536) count = 65536;
    int c2 = 64 + (lane & 31);             // upper lanes duplicate lanes 0..31
    int wid = blockIdx.x * 4 + wv;

    for (int base = wid * 4; base < count; base += MSG_NWAVES * 4) {
        int   gei[4];
        float wgt[4];
        bool  val[4];
        #pragma unroll
        for (int e = 0; e < 4; ++e) {
            int ai = base + e;
            val[e] = (ai < count);
            int as = val[e] ? ai : base;   // safe clamp; padded lanes weight 0
            gei[e] = glist[as];
            wgt[e] = val[e] ? gw[ai] : 0.0f;
        }
        // gather 4 edges' inputs -> LDS (wave-local, no barrier needed)
        #pragma unroll
        for (int e = 0; e < 4; ++e) {
            int g = gei[e];
            int b = g >> 16;
            int e0 = edges[2 * g], e1 = edges[2 * g + 1];
            const float* n0 = nodes + ((size_t)b * Nn + e0) * 96;
            const float* n1 = nodes + ((size_t)b * Nn + e1) * 96;
            const float* ep = ef + (size_t)g * 32;
            #pragma unroll
            for (int ii = 0; ii < 4; ++ii) {
                int i = ii * 64 + lane;
                if (i < 224) {
                    float v = (i < 96) ? n0[i] : (i < 192) ? n1[i - 96] : ep[i - 192];
                    sin_s[wv][e][i] = v;
                }
            }
        }
        // quad matvec: one Wm row pair feeds 8 FMAs
        float acc[4][2];
        #pragma unroll
        for (int e = 0; e < 4; ++e) { acc[e][0] = bm[lane]; acc[e][1] = bm[c2]; }
        #pragma unroll 8
        for (int i = 0; i < 224; ++i) {
            float w1 = Wm[i * 96 + lane];
            float w2 = Wm[i * 96 + c2];
            #pragma unroll
            for (int e = 0; e < 4; ++e) {
                float a = sin_s[wv][e][i];             // LDS broadcast
                acc[e][0] = fmaf(a, w1, acc[e][0]);
                acc[e][1] = fmaf(a, w2, acc[e][1]);
            }
        }
        // per-edge GELU + LayerNorm + weight + scatter
        #pragma unroll
        for (int e = 0; e < 4; ++e) {
            if (!val[e]) continue;
            float y1 = gelu_exact(acc[e][0]);
            float y2 = gelu_exact(acc[e][1]);
            float c2v = (lane < 32) ? y2 : 0.0f;
            float sum  = y1 + c2v;
            float sum2 = y1 * y1 + c2v * c2v;
            #pragma unroll
            for (int off = 1; off < 64; off <<= 1) {
                sum  += __shfl_xor(sum, off);
                sum2 += __shfl_xor(sum2, off);
            }
            float mean = sum * (1.0f / 96.0f);
            float var  = sum2 * (1.0f / 96.0f) - mean * mean;
            float rs   = rsqrtf(var + 1e-3f);
            int g = gei[e];
            int b = g >> 16;
            int e1 = edges[2 * g + 1];
            float* aggp = agg + ((size_t)b * Nn + e1) * 96;
            float* wmp  = out_wm + (size_t)g * 96;
            float o1 = ((y1 - mean) * rs * g1[lane] + b1[lane]) * wgt[e];
            wmp[lane] = o1;
            atomicAdd(&aggp[lane], o1);
            if (lane < 32) {
                float o2 = ((y2 - mean) * rs * g1[c2] + b1[c2]) * wgt[e];
                wmp[c2] = o2;
                atomicAdd(&aggp[c2], o2);
            }
        }
    }
}

// Pass 2: q/k/v/gate projections. x = [nodes, agg] (4096 x 192) @ W (192 x 96) + b.
// Output HEAD-MAJOR [B,H,N,8] via LDS re-stage -> fully coalesced float4 stores.
// m=0 blocks additionally zero out_wm chunks [768, 896).
__global__ void proj_kernel(const float* __restrict__ nodes, const float* __restrict__ agg,
                            const float* __restrict__ Wq, const float* __restrict__ bq,
                            const float* __restrict__ Wk, const float* __restrict__ bk,
                            const float* __restrict__ Wv, const float* __restrict__ bv,
                            const float* __restrict__ Wg, const float* __restrict__ bg,
                            float* __restrict__ qo, float* __restrict__ ko,
                            float* __restrict__ vo, float* __restrict__ go,
                            const float* __restrict__ dist, const float* __restrict__ sigma,
                            const float* __restrict__ beta, float* __restrict__ out_wm) {
    __shared__ float xs[32][200];   // padded; row byte-stride 800 = 50*16 (16B aligned)
    __shared__ float Wt[64 * 96];
    __shared__ int s_act[256];
    int tid = threadIdx.x;
    int m = blockIdx.y;
    if (m == 0) {
        zero_wm_chunk(768 + blockIdx.x, dist, sigma, beta, out_wm, tid, 256, s_act);
    }
    const float* W    = (m == 0) ? Wq : (m == 1) ? Wk : (m == 2) ? Wv : Wg;
    const float* bias = (m == 0) ? bq : (m == 1) ? bk : (m == 2) ? bv : bg;
    float* outp       = (m == 0) ? qo : (m == 1) ? ko : (m == 2) ? vo : go;
    int row0 = blockIdx.x * 32;
    int b = row0 >> 10, n0 = row0 & 1023;
    for (int i = tid; i < 32 * 192; i += 256) {
        int r = i / 192, k = i % 192;
        size_t row = row0 + r;
        xs[r][k] = (k < 96) ? nodes[row * 96 + k] : agg[row * 96 + (k - 96)];
    }
    int rg = tid >> 4;              // 0..15 (2 rows each)
    int cg = tid & 15;              // 0..15 (6 cols each)
    float acc[12];
    #pragma unroll
    for (int c = 0; c < 12; ++c) acc[c] = 0.0f;
    for (int kc = 0; kc < 3; ++kc) {
        __syncthreads();
        {
            float4* Wt4 = (float4*)Wt;
            const float4* Wg4 = (const float4*)(W + kc * 64 * 96);
            for (int i = tid; i < 1536; i += 256) Wt4[i] = Wg4[i];
        }
        __syncthreads();
        #pragma unroll 4
        for (int k = 0; k < 64; ++k) {
            float a0 = xs[rg * 2 + 0][kc * 64 + k];
            float a1 = xs[rg * 2 + 1][kc * 64 + k];
            #pragma unroll
            for (int c = 0; c < 6; ++c) {
                float wv_ = Wt[k * 96 + cg * 6 + c];
                acc[c]     = fmaf(a0, wv_, acc[c]);
                acc[6 + c] = fmaf(a1, wv_, acc[6 + c]);
            }
        }
    }
    // epilogue into LDS (cols 0..95 don't overlap kc=2's read range 128..191)
    #pragma unroll
    for (int i = 0; i < 2; ++i) {
        #pragma unroll
        for (int c = 0; c < 6; ++c) {
            int col = cg * 6 + c;
            float v = acc[i * 6 + c] + bias[col];
            if (m == 3) v = 1.0f / (1.0f + expf(-v));
            xs[rg * 2 + i][col] = v;
        }
    }
    __syncthreads();
    // coalesced store: per head h, 32 rows * 8 floats = contiguous 64 float4
    float4* out4 = (float4*)outp;
    for (int j = tid; j < 768; j += 256) {
        int h = j >> 6, idx = j & 63;
        int r = idx >> 1, half = idx & 1;
        float4 v = *(const float4*)&xs[r][h * 8 + half * 4];
        out4[(((size_t)b * Hn + h) * Nn + n0) * 2 + idx] = v;
    }
}

// Pass 3: split-KV attention, head-major, no-max softmax (scores bounded
// ~|s|<20 << 88 f32 exp overflow). Each block also zeroes one out_wm chunk.
__global__ __launch_bounds__(512, 6) void attn_kernel(
        const float* __restrict__ qp, const float* __restrict__ kp,
        const float* __restrict__ vp, const float* __restrict__ gp,
        float* __restrict__ ao,
        const float* __restrict__ dist, const float* __restrict__ sigma,
        const float* __restrict__ beta, float* __restrict__ out_wm) {
    __shared__ float sl[512];
    __shared__ float sacc[512][9];
    __shared__ int s_act[256];
    int tid = threadIdx.x;
    zero_wm_chunk(blockIdx.y * 16 + blockIdx.x, dist, sigma, beta, out_wm, tid, 512, s_act);
    int bh = blockIdx.y;                    // b*H + h
    int lane = tid & 63;
    int w = __builtin_amdgcn_readfirstlane(tid >> 6);
    int n = blockIdx.x * 64 + lane;
    size_t hb = (size_t)bh * (Nn * 8);
    size_t qoff = hb + (size_t)n * 8;

    const float scale = 0.35355339059327376f;  // 1/sqrt(8)
    float4 q0 = *(const float4*)&qp[qoff];
    float4 q1 = *(const float4*)&qp[qoff + 4];
    q0.x *= scale; q0.y *= scale; q0.z *= scale; q0.w *= scale;
    q1.x *= scale; q1.y *= scale; q1.z *= scale; q1.w *= scale;

    const float4* kc4 = (const float4*)(kp + hb) + (size_t)w * 256;  // 128 keys
    const float4* vc4 = (const float4*)(vp + hb) + (size_t)w * 256;

    float l = 0.0f;
    float a0 = 0, a1 = 0, a2 = 0, a3 = 0, a4 = 0, a5 = 0, a6 = 0, a7 = 0;
    for (int g = 0; g < 32; ++g) {          // 4 keys per group
        float4 T[8];
        #pragma unroll
        for (int i = 0; i < 8; ++i) T[i] = kc4[g * 8 + i];   // K group
        float s[4];
        #pragma unroll
        for (int jj = 0; jj < 4; ++jj) {
            float4 k0 = T[jj * 2], k1 = T[jj * 2 + 1];
            s[jj] = q0.x * k0.x + q0.y * k0.y + q0.z * k0.z + q0.w * k0.w +
                    q1.x * k1.x + q1.y * k1.y + q1.z * k1.z + q1.w * k1.w;
        }
        #pragma unroll
        for (int i = 0; i < 8; ++i) T[i] = vc4[g * 8 + i];   // reuse regs: V group
        float p[4];
        #pragma unroll
        for (int jj = 0; jj < 4; ++jj) p[jj] = __expf(s[jj]);
        l += (p[0] + p[1]) + (p[2] + p[3]);
        #pragma unroll
        for (int jj = 0; jj < 4; ++jj) {
            float4 v0 = T[jj * 2], v1 = T[jj * 2 + 1];
            a0 = fmaf(p[jj], v0.x, a0);  a1 = fmaf(p[jj], v0.y, a1);
            a2 = fmaf(p[jj], v0.z, a2);  a3 = fmaf(p[jj], v0.w, a3);
            a4 = fmaf(p[jj], v1.x, a4);  a5 = fmaf(p[jj], v1.y, a5);
            a6 = fmaf(p[jj], v1.z, a6);  a7 = fmaf(p[jj], v1.w, a7);
        }
    }
    sl[tid] = l;
    sacc[tid][0] = a0; sacc[tid][1] = a1; sacc[tid][2] = a2; sacc[tid][3] = a3;
    sacc[tid][4] = a4; sacc[tid][5] = a5; sacc[tid][6] = a6; sacc[tid][7] = a7;
    __syncthreads();
    if (tid < 64) {
        float L = 0.0f;
        float o[8] = {0, 0, 0, 0, 0, 0, 0, 0};
        #pragma unroll
        for (int i = 0; i < 8; ++i) {
            L += sl[tid + 64 * i];
            #pragma unroll
            for (int d = 0; d < 8; ++d)
                o[d] += sacc[tid + 64 * i][d];
        }
        float invL = 1.0f / L;
        float4 g0 = *(const float4*)&gp[qoff];
        float4 g1v = *(const float4*)&gp[qoff + 4];
        float4 r0 = make_float4(o[0] * invL * g0.x, o[1] * invL * g0.y,
                                o[2] * invL * g0.z, o[3] * invL * g0.w);
        float4 r1 = make_float4(o[4] * invL * g1v.x, o[5] * invL * g1v.y,
                                o[6] * invL * g1v.z, o[7] * invL * g1v.w);
        *(float4*)&ao[qoff] = r0;
        *(float4*)&ao[qoff + 4] = r1;
    }
}

// Pass 4: out @ Wo + bo -> GELU -> LayerNorm. 512 thr, 32 rows/block,
// coalesced float4 gather of head-major ao via LDS.
// Each block additionally zeroes one out_wm chunk [896, 1024).
__global__ __launch_bounds__(512) void out_kernel(
        const float* __restrict__ ao, const float* __restrict__ Wo,
        const float* __restrict__ bo, const float* __restrict__ g2,
        const float* __restrict__ b2, float* __restrict__ out0,
        const float* __restrict__ dist, const float* __restrict__ sigma,
        const float* __restrict__ beta, float* __restrict__ out_wm) {
    __shared__ float Wsh[96 * 96];
    __shared__ float as_[32][104];   // row byte-stride 416 = 26*16 (16B aligned)
    __shared__ int s_act[256];
    int tid = threadIdx.x;
    zero_wm_chunk(896 + blockIdx.x, dist, sigma, beta, out_wm, tid, 512, s_act);
    int row0 = blockIdx.x * 32;
    int b = row0 >> 10, n0 = row0 & 1023;
    {
        float4* W4 = (float4*)Wsh;
        const float4* Wg4 = (const float4*)Wo;
        for (int i = tid; i < 2304; i += 512) W4[i] = Wg4[i];
    }
    const float4* ao4 = (const float4*)ao;
    for (int j = tid; j < 768; j += 512) {
        int h = j >> 6, idx = j & 63;
        int r = idx >> 1, half = idx & 1;
        float4 v = ao4[(((size_t)b * Hn + h) * Nn + n0) * 2 + idx];
        *(float4*)&as_[r][h * 8 + half * 4] = v;
    }
    __syncthreads();
    int r = tid >> 4, cg = tid & 15;   // 32 rows, 6 cols per thread
    float acc[6];
    #pragma unroll
    for (int c = 0; c < 6; ++c) acc[c] = 0.0f;
    for (int k = 0; k < 96; ++k) {
        float a = as_[r][k];
        #pragma unroll
        for (int c = 0; c < 6; ++c)
            acc[c] = fmaf(a, Wsh[k * 96 + cg * 6 + c], acc[c]);
    }
    float yv[6];
    float sum = 0.0f, sum2 = 0.0f;
    #pragma unroll
    for (int c = 0; c < 6; ++c) {
        float t = acc[c] + bo[cg * 6 + c];
        float g = gelu_exact(t);
        yv[c] = g;
        sum += g; sum2 += g * g;
    }
    #pragma unroll
    for (int off = 1; off < 16; off <<= 1) {
        sum  += __shfl_xor(sum, off);
        sum2 += __shfl_xor(sum2, off);
    }
    float mean = sum * (1.0f / 96.0f);
    float var  = sum2 * (1.0f / 96.0f) - mean * mean;
    float rs   = rsqrtf(var + 1e-3f);
    size_t row = row0 + r;
    #pragma unroll
    for (int c = 0; c < 6; ++c)
        out0[row * 96 + cg * 6 + c] = (yv[c] - mean) * rs * g2[cg * 6 + c] + b2[cg * 6 + c];
}

extern "C" void kernel_launch(void* const* d_in, const int* in_sizes, int n_in,
                              void* d_out, int out_size, void* d_ws, size_t ws_size,
                              hipStream_t stream) {
    const float* nodes = (const float*)d_in[0];
    const float* ef    = (const float*)d_in[1];
    const float* dist  = (const float*)d_in[2];
    const int*   edges = (const int*)d_in[3];
    const float* Wm = (const float*)d_in[4];
    const float* bm = (const float*)d_in[5];
    const float* g1 = (const float*)d_in[6];
    const float* b1 = (const float*)d_in[7];
    const float* Wq = (const float*)d_in[8];
    const float* bq = (const float*)d_in[9];
    const float* Wk = (const float*)d_in[10];
    const float* bk = (const float*)d_in[11];
    const float* Wv = (const float*)d_in[12];
    const float* bv = (const float*)d_in[13];
    const float* Wg = (const float*)d_in[14];
    const float* bg = (const float*)d_in[15];
    const float* Wo = (const float*)d_in[16];
    const float* bo = (const float*)d_in[17];
    const float* g2 = (const float*)d_in[18];
    const float* b2 = (const float*)d_in[19];
    const float* sigma = (const float*)d_in[20];
    const float* beta  = (const float*)d_in[21];

    float* out = (float*)d_out;
    float* ws  = (float*)d_ws;

    float* agg  = ws + WS_AGG;
    float* qb   = ws + WS_Q;
    float* kb   = ws + WS_K;
    float* vb   = ws + WS_V;
    float* gwb  = ws + WS_G;
    float* aob  = ws + WS_AO;
    int*   glist = (int*)(ws + WS_LIST);
    float* glw   = ws + WS_LW;
    int*   gcnt  = (int*)(ws + WS_CNT);

    zero_kernel<<<192, 256, 0, stream>>>(agg, gcnt);

    scan_kernel<<<Bn * En / 1024, 1024, 0, stream>>>(
        dist, edges, sigma, beta, out + OUT_DIST, out + OUT_EDGE, glist, glw, gcnt);

    msg_kernel<<<256, 256, 0, stream>>>(
        glist, glw, gcnt, edges, nodes, ef, Wm, bm, g1, b1, out + OUT_WM, agg);

    dim3 gp_(128, 4);
    proj_kernel<<<gp_, 256, 0, stream>>>(
        nodes, agg, Wq, bq, Wk, bk, Wv, bv, Wg, bg, qb, kb, vb, gwb,
        dist, sigma, beta, out + OUT_WM);

    dim3 ga(16, Bn * Hn);
    attn_kernel<<<ga, 512, 0, stream>>>(qb, kb, vb, gwb, aob,
                                        dist, sigma, beta, out + OUT_WM);

    out_kernel<<<Bn * Nn / 32, 512, 0, stream>>>(aob, Wo, bo, g2, b2, out + OUT_UPD,
                                                 dist, sigma, beta, out + OUT_WM);
}

// Round 7
// 112.159 us; speedup vs baseline: 7.4234x; 1.0153x over previous
//
#include <hip/hip_runtime.h>
#include <math.h>

#define Bn 4
#define Nn 1024
#define En 65536
#define Fn 96
#define FEn 32
#define Hn 12
// K dim for message MLP: 2F+FE = 224

// ---- out layout (floats) ----
#define OUT_UPD  0
#define OUT_WM   393216LL             // B*N*F
#define OUT_DIST 25559040LL           // + B*E*F
#define OUT_EDGE 25821184LL           // + B*E

// ---- ws layout (float words) ----
#define WS_AGG  0
#define WS_Q    393216
#define WS_K    786432
#define WS_V    1179648
#define WS_G    1572864
#define WS_AO   1966080
#define WS_LIST 2359296   // int: compacted active-edge ids (cap 65536)
#define WS_LW   2424832   // float: per-active gaussian weight
#define WS_CNT  2490368   // int: active count

#define MSG_NWAVES 1024   // 256 blocks * 4 waves; 4 edges/wave -> 4096 cap/round

typedef __attribute__((ext_vector_type(8))) short bf16x8;
typedef __attribute__((ext_vector_type(4))) float f32x4;

__device__ __forceinline__ float gelu_exact(float x) {
    return 0.5f * x * (1.0f + erff(x * 0.70710678118654752f));
}

// pack two f32 -> (lo,hi) bf16 pair in one u32 (RNE), per guide T12 syntax
__device__ __forceinline__ unsigned cvtpk_bf16(float lo, float hi) {
    unsigned r;
    asm("v_cvt_pk_bf16_f32 %0, %1, %2" : "=v"(r) : "v"(lo), "v"(hi));
    return r;
}

// Zero the inactive rows of one 256-edge chunk of out_wm (96 KB).
// Active test is bitwise-identical to scan's, so active/inactive rows partition.
__device__ __forceinline__ void zero_wm_chunk(int c, const float* __restrict__ dist,
                                              const float* __restrict__ sigma,
                                              const float* __restrict__ beta,
                                              float* __restrict__ out_wm,
                                              int tid, int nthr, int* s_act) {
    if (tid < 256) {
        int ge = c * 256 + tid;
        float d = dist[ge];
        float sg = sigma[0], bt = beta[0];
        float t = d * d / (2.0f * sg * sg);
        s_act[tid] = (powf(t, bt) < 90.0f) ? 1 : 0;
    }
    __syncthreads();
    const float4 z = make_float4(0.f, 0.f, 0.f, 0.f);
    float4* wm4 = (float4*)out_wm + (size_t)c * 6144;   // 256 rows * 24 float4
    for (int p = tid; p < 6144; p += nthr) {
        if (!s_act[p / 24]) wm4[p] = z;
    }
}

// Pass 0: zero agg (1.5 MB) + counter.
__global__ void zero_kernel(float* __restrict__ agg, int* __restrict__ gcnt) {
    int i = blockIdx.x * 256 + threadIdx.x;
    const float4 z = make_float4(0.f, 0.f, 0.f, 0.f);
    float4* p = (float4*)agg;
    p[i] = z;
    p[i + 49152] = z;
    if (i == 0) gcnt[0] = 0;
}

// Pass 1a (scan): per-edge gaussian gate; copy dist/edges to out; compact
// actives into a global list. ONE atomic per 1024-thread block (LDS
// aggregation).
__global__ __launch_bounds__(1024) void scan_kernel(
        const float* __restrict__ dist, const int* __restrict__ edges,
        const float* __restrict__ sigma, const float* __restrict__ beta,
        float* __restrict__ out_dist, float* __restrict__ out_edges,
        int* __restrict__ glist, float* __restrict__ gw,
        int* __restrict__ gcnt) {
    __shared__ int wcnt[16], wbase[16], blkbase;
    int tid = threadIdx.x;
    int lane = tid & 63, wv = tid >> 6;
    int ge = blockIdx.x * 1024 + tid;
    float d = dist[ge];
    out_dist[ge] = d;
    int e0 = edges[2 * ge], e1 = edges[2 * ge + 1];
    *(float2*)&out_edges[2 * ge] = make_float2((float)e0, (float)e1);
    float sg = sigma[0], bt = beta[0];
    float t  = d * d / (2.0f * sg * sg);
    float tp = powf(t, bt);
    bool active = (tp < 90.0f);            // else w underflows f32 (ref < 1e-39)
    float w = active ? expf(-tp) : 0.0f;

    unsigned long long mask = __ballot(active);
    int lp = __popcll(mask & ((1ull << lane) - 1ull));
    if (lane == 0) wcnt[wv] = __popcll(mask);
    __syncthreads();
    if (tid == 0) {
        int a = 0;
        #pragma unroll
        for (int i = 0; i < 16; ++i) { wbase[i] = a; a += wcnt[i]; }
        blkbase = a ? atomicAdd(gcnt, a) : 0;
    }
    __syncthreads();
    if (active) {
        int pos = blkbase + wbase[wv] + lp;
        if (pos < 65536) { glist[pos] = ge; gw[pos] = w; }
    }
}

// Pass 1b (msg): four edges per wave; Wm row loads amortized across 8 FMAs.
__global__ __launch_bounds__(256) void msg_kernel(
        const int* __restrict__ glist, const float* __restrict__ gw,
        const int* __restrict__ gcnt, const int* __restrict__ edges,
        const float* __restrict__ nodes, const float* __restrict__ ef,
        const float* __restrict__ Wm, const float* __restrict__ bm,
        const float* __restrict__ g1, const float* __restrict__ b1,
        float* __restrict__ out_wm, float* __restrict__ agg) {
    __shared__ float sin_s[4][4][232];     // [wave][edge-in-quad][224+pad]
    int tid = threadIdx.x;
    int lane = tid & 63, wv = tid >> 6;
    int count = gcnt[0];
    if (count > 65536) count = 65536;
    int c2 = 64 + (lane & 31);             // upper lanes duplicate lanes 0..31
    int wid = blockIdx.x * 4 + wv;

    for (int base = wid * 4; base < count; base += MSG_NWAVES * 4) {
        int   gei[4];
        float wgt[4];
        bool  val[4];
        #pragma unroll
        for (int e = 0; e < 4; ++e) {
            int ai = base + e;
            val[e] = (ai < count);
            int as = val[e] ? ai : base;   // safe clamp; padded lanes weight 0
            gei[e] = glist[as];
            wgt[e] = val[e] ? gw[ai] : 0.0f;
        }
        // gather 4 edges' inputs -> LDS (wave-local, no barrier needed)
        #pragma unroll
        for (int e = 0; e < 4; ++e) {
            int g = gei[e];
            int b = g >> 16;
            int e0 = edges[2 * g], e1 = edges[2 * g + 1];
            const float* n0 = nodes + ((size_t)b * Nn + e0) * 96;
            const float* n1 = nodes + ((size_t)b * Nn + e1) * 96;
            const float* ep = ef + (size_t)g * 32;
            #pragma unroll
            for (int ii = 0; ii < 4; ++ii) {
                int i = ii * 64 + lane;
                if (i < 224) {
                    float v = (i < 96) ? n0[i] : (i < 192) ? n1[i - 96] : ep[i - 192];
                    sin_s[wv][e][i] = v;
                }
            }
        }
        // quad matvec: one Wm row pair feeds 8 FMAs
        float acc[4][2];
        #pragma unroll
        for (int e = 0; e < 4; ++e) { acc[e][0] = bm[lane]; acc[e][1] = bm[c2]; }
        #pragma unroll 8
        for (int i = 0; i < 224; ++i) {
            float w1 = Wm[i * 96 + lane];
            float w2 = Wm[i * 96 + c2];
            #pragma unroll
            for (int e = 0; e < 4; ++e) {
                float a = sin_s[wv][e][i];             // LDS broadcast
                acc[e][0] = fmaf(a, w1, acc[e][0]);
                acc[e][1] = fmaf(a, w2, acc[e][1]);
            }
        }
        // per-edge GELU + LayerNorm + weight + scatter
        #pragma unroll
        for (int e = 0; e < 4; ++e) {
            if (!val[e]) continue;
            float y1 = gelu_exact(acc[e][0]);
            float y2 = gelu_exact(acc[e][1]);
            float c2v = (lane < 32) ? y2 : 0.0f;
            float sum  = y1 + c2v;
            float sum2 = y1 * y1 + c2v * c2v;
            #pragma unroll
            for (int off = 1; off < 64; off <<= 1) {
                sum  += __shfl_xor(sum, off);
                sum2 += __shfl_xor(sum2, off);
            }
            float mean = sum * (1.0f / 96.0f);
            float var  = sum2 * (1.0f / 96.0f) - mean * mean;
            float rs   = rsqrtf(var + 1e-3f);
            int g = gei[e];
            int b = g >> 16;
            int e1 = edges[2 * g + 1];
            float* aggp = agg + ((size_t)b * Nn + e1) * 96;
            float* wmp  = out_wm + (size_t)g * 96;
            float o1 = ((y1 - mean) * rs * g1[lane] + b1[lane]) * wgt[e];
            wmp[lane] = o1;
            atomicAdd(&aggp[lane], o1);
            if (lane < 32) {
                float o2 = ((y2 - mean) * rs * g1[c2] + b1[c2]) * wgt[e];
                wmp[c2] = o2;
                atomicAdd(&aggp[c2], o2);
            }
        }
    }
}

// Pass 2: q/k/v/gate projections (unchanged from round 6).
__global__ void proj_kernel(const float* __restrict__ nodes, const float* __restrict__ agg,
                            const float* __restrict__ Wq, const float* __restrict__ bq,
                            const float* __restrict__ Wk, const float* __restrict__ bk,
                            const float* __restrict__ Wv, const float* __restrict__ bv,
                            const float* __restrict__ Wg, const float* __restrict__ bg,
                            float* __restrict__ qo, float* __restrict__ ko,
                            float* __restrict__ vo, float* __restrict__ go,
                            const float* __restrict__ dist, const float* __restrict__ sigma,
                            const float* __restrict__ beta, float* __restrict__ out_wm) {
    __shared__ float xs[32][200];   // padded; row byte-stride 800 = 50*16 (16B aligned)
    __shared__ float Wt[64 * 96];
    __shared__ int s_act[256];
    int tid = threadIdx.x;
    int m = blockIdx.y;
    if (m == 0) {
        zero_wm_chunk(768 + blockIdx.x, dist, sigma, beta, out_wm, tid, 256, s_act);
    }
    const float* W    = (m == 0) ? Wq : (m == 1) ? Wk : (m == 2) ? Wv : Wg;
    const float* bias = (m == 0) ? bq : (m == 1) ? bk : (m == 2) ? bv : bg;
    float* outp       = (m == 0) ? qo : (m == 1) ? ko : (m == 2) ? vo : go;
    int row0 = blockIdx.x * 32;
    int b = row0 >> 10, n0 = row0 & 1023;
    for (int i = tid; i < 32 * 192; i += 256) {
        int r = i / 192, k = i % 192;
        size_t row = row0 + r;
        xs[r][k] = (k < 96) ? nodes[row * 96 + k] : agg[row * 96 + (k - 96)];
    }
    int rg = tid >> 4;              // 0..15 (2 rows each)
    int cg = tid & 15;              // 0..15 (6 cols each)
    float acc[12];
    #pragma unroll
    for (int c = 0; c < 12; ++c) acc[c] = 0.0f;
    for (int kc = 0; kc < 3; ++kc) {
        __syncthreads();
        {
            float4* Wt4 = (float4*)Wt;
            const float4* Wg4 = (const float4*)(W + kc * 64 * 96);
            for (int i = tid; i < 1536; i += 256) Wt4[i] = Wg4[i];
        }
        __syncthreads();
        #pragma unroll 4
        for (int k = 0; k < 64; ++k) {
            float a0 = xs[rg * 2 + 0][kc * 64 + k];
            float a1 = xs[rg * 2 + 1][kc * 64 + k];
            #pragma unroll
            for (int c = 0; c < 6; ++c) {
                float wv_ = Wt[k * 96 + cg * 6 + c];
                acc[c]     = fmaf(a0, wv_, acc[c]);
                acc[6 + c] = fmaf(a1, wv_, acc[6 + c]);
            }
        }
    }
    // epilogue into LDS (cols 0..95 don't overlap kc=2's read range 128..191)
    #pragma unroll
    for (int i = 0; i < 2; ++i) {
        #pragma unroll
        for (int c = 0; c < 6; ++c) {
            int col = cg * 6 + c;
            float v = acc[i * 6 + c] + bias[col];
            if (m == 3) v = 1.0f / (1.0f + expf(-v));
            xs[rg * 2 + i][col] = v;
        }
    }
    __syncthreads();
    // coalesced store: per head h, 32 rows * 8 floats = contiguous 64 float4
    float4* out4 = (float4*)outp;
    for (int j = tid; j < 768; j += 256) {
        int h = j >> 6, idx = j & 63;
        int r = idx >> 1, half = idx & 1;
        float4 v = *(const float4*)&xs[r][h * 8 + half * 4];
        out4[(((size_t)b * Hn + h) * Nn + n0) * 2 + idx] = v;
    }
}

// Pass 3: MFMA bf16 attention. Per block: one head (blockIdx.y), 64 q-rows
// (blockIdx.x), 4 waves x 16 q-rows. K staged bf16 [1024][8] in LDS; V staged
// TRANSPOSED bf16 [9][1024+pad] with row 8 = ones: the PV MFMA accumulates
// the softmax denominator L into O's column 8 for free. d=8..31 zero-padded
// in the 16x16x32 MFMA. No-max softmax (scores |s|<~20 << 88 overflow).
// P -> A-frag conversion via wave-local LDS bf16 round-trip.
__global__ __launch_bounds__(256, 4) void attn_kernel(
        const float* __restrict__ qp, const float* __restrict__ kp,
        const float* __restrict__ vp, const float* __restrict__ gp,
        float* __restrict__ ao,
        const float* __restrict__ dist, const float* __restrict__ sigma,
        const float* __restrict__ beta, float* __restrict__ out_wm) {
    __shared__ __align__(16) unsigned short K_s[1024][8];     // 16 KB, row=16B
    __shared__ __align__(16) unsigned short Vt_s[9][1032];    // 18.1 KB, stride 2064B
    __shared__ __align__(16) unsigned short P_s[4][16][32];   // 4 KB, per-wave
    __shared__ int s_act[256];
    int tid = threadIdx.x;
    zero_wm_chunk(blockIdx.y * 16 + blockIdx.x, dist, sigma, beta, out_wm, tid, 256, s_act);

    int bh = blockIdx.y;                    // b*H + h
    int lane = tid & 63, wv = tid >> 6;
    size_t hb = (size_t)bh * (Nn * 8);
    const float* kc = kp + hb;
    const float* vc = vp + hb;

    // ---- stage K as bf16 [k][d] (global order == LDS order) ----
    {
        const float2* k2 = (const float2*)kc;
        unsigned* kw = (unsigned*)&K_s[0][0];
        for (int i = tid; i < 4096; i += 256) {
            float2 v = k2[i];
            kw[i] = cvtpk_bf16(v.x, v.y);
        }
    }
    // ---- stage V transposed: Vt[n][k] = V[k][n]; row 8 = 1.0 ----
    for (int i = tid; i < 8192; i += 256) {
        float v = vc[i];
        int k = i >> 3, n = i & 7;
        Vt_s[n][k] = (unsigned short)cvtpk_bf16(v, v);
    }
    {
        unsigned* ow = (unsigned*)&Vt_s[8][0];
        for (int i = tid; i < 516; i += 256) ow[i] = 0x3F803F80u;  // bf16(1.0) x2
    }

    // ---- Q A-frag (16 q-rows per wave, scaled by 1/sqrt(8)) ----
    const float scale = 0.35355339059327376f;
    int qbase = blockIdx.x * 64 + wv * 16;
    bf16x8 aq = {0, 0, 0, 0, 0, 0, 0, 0};
    if (lane < 16) {
        const float* qr = qp + hb + (size_t)(qbase + lane) * 8;
        float4 qa = *(const float4*)qr;
        float4 qb2 = *(const float4*)(qr + 4);
        union { unsigned u[4]; bf16x8 v; } U;
        U.u[0] = cvtpk_bf16(qa.x * scale, qa.y * scale);
        U.u[1] = cvtpk_bf16(qa.z * scale, qa.w * scale);
        U.u[2] = cvtpk_bf16(qb2.x * scale, qb2.y * scale);
        U.u[3] = cvtpk_bf16(qb2.z * scale, qb2.w * scale);
        aq = U.v;
    }
    __syncthreads();

    // ---- main loop: 32 chunks of 32 keys (2 x 16-key MFMA tiles) ----
    const bf16x8 zero8 = {0, 0, 0, 0, 0, 0, 0, 0};
    const f32x4 zero4 = {0.f, 0.f, 0.f, 0.f};
    f32x4 o = zero4;
    int n16 = lane & 15, grp = lane >> 4;
    for (int c = 0; c < 32; ++c) {
        bf16x8 bk0 = zero8, bk1 = zero8;
        if (lane < 16) {
            bk0 = *(const bf16x8*)&K_s[c * 32 + lane][0];
            bk1 = *(const bf16x8*)&K_s[c * 32 + 16 + lane][0];
        }
        f32x4 s0 = __builtin_amdgcn_mfma_f32_16x16x32_bf16(aq, bk0, zero4, 0, 0, 0);
        f32x4 s1 = __builtin_amdgcn_mfma_f32_16x16x32_bf16(aq, bk1, zero4, 0, 0, 0);
        #pragma unroll
        for (int r = 0; r < 4; ++r) {
            unsigned pk = cvtpk_bf16(__expf(s0[r]), __expf(s1[r]));
            int row = grp * 4 + r;
            P_s[wv][row][n16]      = (unsigned short)pk;          // tile0 col
            P_s[wv][row][16 + n16] = (unsigned short)(pk >> 16);  // tile1 col
        }
        // wave-local LDS write->read (compiler inserts lgkmcnt)
        bf16x8 pa = *(const bf16x8*)&P_s[wv][n16][grp * 8];
        bf16x8 bv = zero8;
        if (n16 <= 8) bv = *(const bf16x8*)&Vt_s[n16][c * 32 + grp * 8];
        o = __builtin_amdgcn_mfma_f32_16x16x32_bf16(pa, bv, o, 0, 0, 0);
    }

    // ---- epilogue: L lives in O column 8; divide + gate + store ----
    #pragma unroll
    for (int r = 0; r < 4; ++r) {
        float L = __shfl(o[r], (lane & 48) | 8);
        if (n16 < 8) {
            int q = qbase + grp * 4 + r;
            size_t off = hb + (size_t)q * 8 + n16;
            ao[off] = o[r] / L * gp[off];
        }
    }
}

// Pass 4: out @ Wo + bo -> GELU -> LayerNorm (unchanged from round 6).
__global__ __launch_bounds__(512) void out_kernel(
        const float* __restrict__ ao, const float* __restrict__ Wo,
        const float* __restrict__ bo, const float* __restrict__ g2,
        const float* __restrict__ b2, float* __restrict__ out0,
        const float* __restrict__ dist, const float* __restrict__ sigma,
        const float* __restrict__ beta, float* __restrict__ out_wm) {
    __shared__ float Wsh[96 * 96];
    __shared__ float as_[32][104];   // row byte-stride 416 = 26*16 (16B aligned)
    __shared__ int s_act[256];
    int tid = threadIdx.x;
    zero_wm_chunk(896 + blockIdx.x, dist, sigma, beta, out_wm, tid, 512, s_act);
    int row0 = blockIdx.x * 32;
    int b = row0 >> 10, n0 = row0 & 1023;
    {
        float4* W4 = (float4*)Wsh;
        const float4* Wg4 = (const float4*)Wo;
        for (int i = tid; i < 2304; i += 512) W4[i] = Wg4[i];
    }
    const float4* ao4 = (const float4*)ao;
    for (int j = tid; j < 768; j += 512) {
        int h = j >> 6, idx = j & 63;
        int r = idx >> 1, half = idx & 1;
        float4 v = ao4[(((size_t)b * Hn + h) * Nn + n0) * 2 + idx];
        *(float4*)&as_[r][h * 8 + half * 4] = v;
    }
    __syncthreads();
    int r = tid >> 4, cg = tid & 15;   // 32 rows, 6 cols per thread
    float acc[6];
    #pragma unroll
    for (int c = 0; c < 6; ++c) acc[c] = 0.0f;
    for (int k = 0; k < 96; ++k) {
        float a = as_[r][k];
        #pragma unroll
        for (int c = 0; c < 6; ++c)
            acc[c] = fmaf(a, Wsh[k * 96 + cg * 6 + c], acc[c]);
    }
    float yv[6];
    float sum = 0.0f, sum2 = 0.0f;
    #pragma unroll
    for (int c = 0; c < 6; ++c) {
        float t = acc[c] + bo[cg * 6 + c];
        float g = gelu_exact(t);
        yv[c] = g;
        sum += g; sum2 += g * g;
    }
    #pragma unroll
    for (int off = 1; off < 16; off <<= 1) {
        sum  += __shfl_xor(sum, off);
        sum2 += __shfl_xor(sum2, off);
    }
    float mean = sum * (1.0f / 96.0f);
    float var  = sum2 * (1.0f / 96.0f) - mean * mean;
    float rs   = rsqrtf(var + 1e-3f);
    size_t row = row0 + r;
    #pragma unroll
    for (int c = 0; c < 6; ++c)
        out0[row * 96 + cg * 6 + c] = (yv[c] - mean) * rs * g2[cg * 6 + c] + b2[cg * 6 + c];
}

extern "C" void kernel_launch(void* const* d_in, const int* in_sizes, int n_in,
                              void* d_out, int out_size, void* d_ws, size_t ws_size,
                              hipStream_t stream) {
    const float* nodes = (const float*)d_in[0];
    const float* ef    = (const float*)d_in[1];
    const float* dist  = (const float*)d_in[2];
    const int*   edges = (const int*)d_in[3];
    const float* Wm = (const float*)d_in[4];
    const float* bm = (const float*)d_in[5];
    const float* g1 = (const float*)d_in[6];
    const float* b1 = (const float*)d_in[7];
    const float* Wq = (const float*)d_in[8];
    const float* bq = (const float*)d_in[9];
    const float* Wk = (const float*)d_in[10];
    const float* bk = (const float*)d_in[11];
    const float* Wv = (const float*)d_in[12];
    const float* bv = (const float*)d_in[13];
    const float* Wg = (const float*)d_in[14];
    const float* bg = (const float*)d_in[15];
    const float* Wo = (const float*)d_in[16];
    const float* bo = (const float*)d_in[17];
    const float* g2 = (const float*)d_in[18];
    const float* b2 = (const float*)d_in[19];
    const float* sigma = (const float*)d_in[20];
    const float* beta  = (const float*)d_in[21];

    float* out = (float*)d_out;
    float* ws  = (float*)d_ws;

    float* agg  = ws + WS_AGG;
    float* qb   = ws + WS_Q;
    float* kb   = ws + WS_K;
    float* vb   = ws + WS_V;
    float* gwb  = ws + WS_G;
    float* aob  = ws + WS_AO;
    int*   glist = (int*)(ws + WS_LIST);
    float* glw   = ws + WS_LW;
    int*   gcnt  = (int*)(ws + WS_CNT);

    zero_kernel<<<192, 256, 0, stream>>>(agg, gcnt);

    scan_kernel<<<Bn * En / 1024, 1024, 0, stream>>>(
        dist, edges, sigma, beta, out + OUT_DIST, out + OUT_EDGE, glist, glw, gcnt);

    msg_kernel<<<256, 256, 0, stream>>>(
        glist, glw, gcnt, edges, nodes, ef, Wm, bm, g1, b1, out + OUT_WM, agg);

    dim3 gp_(128, 4);
    proj_kernel<<<gp_, 256, 0, stream>>>(
        nodes, agg, Wq, bq, Wk, bk, Wv, bv, Wg, bg, qb, kb, vb, gwb,
        dist, sigma, beta, out + OUT_WM);

    dim3 ga(16, Bn * Hn);
    attn_kernel<<<ga, 256, 0, stream>>>(qb, kb, vb, gwb, aob,
                                        dist, sigma, beta, out + OUT_WM);

    out_kernel<<<Bn * Nn / 32, 512, 0, stream>>>(aob, Wo, bo, g2, b2, out + OUT_UPD,
                                                 dist, sigma, beta, out + OUT_WM);
}